// Round 5
// baseline (198.201 us; speedup 1.0000x reference)
//
#include <hip/hip_runtime.h>
#include <math.h>

typedef _Float16 h4  __attribute__((ext_vector_type(4)));
typedef _Float16 h8  __attribute__((ext_vector_type(8)));
typedef __fp16   p2  __attribute__((ext_vector_type(2)));   // cvt_pkrtz result type
typedef float    f4  __attribute__((ext_vector_type(4)));
typedef float    f16x __attribute__((ext_vector_type(16)));

#define NPAIR (8*256*256)
#define BLOCKS 2048               // 2048 blocks x 4 waves x 64 pairs = NPAIR (1 pass/wave)

// 32x32x16 f16 MFMA (gfx950): C/D: col=lane&31, row=(reg&3)+8*(reg>>2)+4*(lane>>5)
// A/B (verified R18 on HW): m/n=lane&31, k=8*(lane>>5)+j
#define MFMA(a,b,c) __builtin_amdgcn_mfma_f32_32x32x16_f16((a),(b),(c),0,0,0)

#define LOG2E 1.44269504088896340736f
#define LN2   0.69314718055994530942f

// Physical->logical channel permutation for 64-wide layers built from two 32x32
// C/D tiles: physical P = 32*mt + (g&3)+8*(g>>2)+4*hi  holds logical channel
// kappa = 32*mt + 16*(g>>3) + 8*hi + (g&7).  With B-frag chunk c built as
// pk8(C[mt=c>>1] regs 8*(c&1)..+7), slot (c,hi,j) then holds logical 16c+8hi+j
// == the MFMA k-index -> layers chain in-register with identity k-axis.
__device__ __forceinline__ int pi64(int P)
{
    int mt = P >> 5, r = P & 31;
    int hi = (r >> 2) & 1;
    int g  = (r & 3) + 4*(r >> 3);
    return 32*mt + 16*(g >> 3) + 8*hi + (g & 7);
}

// A-fragment pool (h8 units):
// [0,128)      W1^T  frags [mt][lane]: elem j: k=8*(lane>>5)+j;
//              k<9 -> W1[k][pi(32mt+(lane&31))]*log2e; k==9 -> b1*log2e; else 0
// [128,1152)   W2'^T frags [(enc*2+mt)*4+c][lane]: k=16c+8*(lane>>5)+j;
//              val = W2[k][P]*fg[enc][P]*ln2, P=pi(32mt+(lane&31))
// [1152,2176)  Wg1^T frags [mt*8+cc][lane]: in=64*(cc>>2)+16*(cc&3)+8*(lane>>5)+j;
//              val = Wg1[in][P]*log2e
__device__ h8 g_frag[2176];
// Epilogue consts in C/D order: flat = base + mt*32 + hi*16 + g:
// [0,128) E-init (enc major)  [128,192) bg1*log2e  [192,256) (Wg2[1]-Wg2[0])*ln2
// [256,320) ln_g*Wo
__device__ float g_cst[320];
__device__ float g_cc[2];         // C0 = sum ln_b*Wo, C1 = sum ln_g*Wo

__global__ void prep_kernel(const float* __restrict__ W1, const float* __restrict__ b1,
                            const float* __restrict__ W2, const float* __restrict__ b2,
                            const float* __restrict__ fgam, const float* __restrict__ fbet,
                            const float* __restrict__ Wg1, const float* __restrict__ bg1,
                            const float* __restrict__ Wg2,
                            const float* __restrict__ ln_g, const float* __restrict__ ln_b,
                            const float* __restrict__ Wo)
{
    int idx = blockIdx.x * 256 + threadIdx.x;
    if (idx < 2176) {
        h8 v;
        if (idx < 128) {
            int mt = idx >> 6, L = idx & 63;
            int hi = L >> 5, m = L & 31;
            int P = pi64(32*mt + m);
#pragma unroll
            for (int j = 0; j < 8; ++j) {
                int k = 8*hi + j;
                float x = (k < 9) ? W1[k*64 + P] : (k == 9 ? b1[P] : 0.f);
                v[j] = (_Float16)(x * LOG2E);
            }
        } else if (idx < 1152) {
            int z = idx - 128; int f = z >> 6, L = z & 63;
            int c = f & 3, mt = (f >> 2) & 1, enc = f >> 3;
            int hi = L >> 5, m = L & 31;
            int P = pi64(32*mt + m);
            float fgv = fgam[enc*64 + P] * LN2;
#pragma unroll
            for (int j = 0; j < 8; ++j) {
                int k = 16*c + 8*hi + j;
                v[j] = (_Float16)(W2[k*64 + P] * fgv);
            }
        } else {
            int z = idx - 1152; int f = z >> 6, L = z & 63;
            int cc = f & 7, mt = f >> 3;
            int hi = L >> 5, m = L & 31;
            int P = pi64(32*mt + m);
#pragma unroll
            for (int j = 0; j < 8; ++j) {
                int in = 64*(cc >> 2) + 16*(cc & 3) + 8*hi + j;
                v[j] = (_Float16)(Wg1[in*64 + P] * LOG2E);
            }
        }
        g_frag[idx] = v;
    } else if (idx >= 4352 && idx < 4416) {
        int k = idx - 4352;
        float c0 = ln_b[k]*Wo[k], c1 = ln_g[k]*Wo[k];
#pragma unroll
        for (int s = 1; s < 64; s <<= 1) {
            c0 += __shfl_xor(c0, s);
            c1 += __shfl_xor(c1, s);
        }
        if (k == 0) { g_cc[0] = c0; g_cc[1] = c1; }
    } else if (idx >= 4608 && idx < 4928) {
        int c = idx - 4608;
        float v;
        if (c < 128) {
            int enc = c >> 6, w = c & 63;
            int mt = w >> 5, hi = (w >> 4) & 1, g = w & 15;
            int P = pi64(32*mt + (g & 3) + 8*(g >> 2) + 4*hi);
            v = fmaf(b2[P], fgam[enc*64 + P], fbet[enc*64 + P]);
        } else if (c < 192) {
            int w = c - 128, mt = w >> 5, hi = (w >> 4) & 1, g = w & 15;
            int P = pi64(32*mt + (g & 3) + 8*(g >> 2) + 4*hi);
            v = bg1[P] * LOG2E;
        } else if (c < 256) {
            int w = c - 192, mt = w >> 5, hi = (w >> 4) & 1, g = w & 15;
            int P = pi64(32*mt + (g & 3) + 8*(g >> 2) + 4*hi);
            v = (Wg2[2*P+1] - Wg2[2*P]) * LN2;
        } else {
            int w = c - 256, mt = w >> 5, hi = (w >> 4) & 1, g = w & 15;
            int P = pi64(32*mt + (g & 3) + 8*(g >> 2) + 4*hi);
            v = ln_g[P] * Wo[P];
        }
        g_cst[c] = v;
    }
}

// x' = x*log2e (folded into weights): x'*sigmoid(x) = log2e*silu(x); trailing ln2
// folded into the consumer. 2 trans + 2 VALU per element.
__device__ __forceinline__ f16x xsig16(f16x v)
{
#pragma unroll
    for (int i = 0; i < 16; ++i)
        v[i] = v[i] * __builtin_amdgcn_rcpf(1.f + __builtin_amdgcn_exp2f(-v[i]));
    return v;
}

template<int B>
__device__ __forceinline__ h8 pk8(const f16x& v)   // C/D regs B..B+7 -> h8 B-frag
{
    p2 a = __builtin_amdgcn_cvt_pkrtz(v[B+0], v[B+1]);
    p2 b = __builtin_amdgcn_cvt_pkrtz(v[B+2], v[B+3]);
    p2 c = __builtin_amdgcn_cvt_pkrtz(v[B+4], v[B+5]);
    p2 d = __builtin_amdgcn_cvt_pkrtz(v[B+6], v[B+7]);
    h8 r;
    r[0]=a[0]; r[1]=a[1]; r[2]=b[0]; r[3]=b[1];
    r[4]=c[0]; r[5]=c[1]; r[6]=d[0]; r[7]=d[1];
    return r;
}

__device__ __forceinline__ unsigned pu(p2 v)
{
    union { p2 p; unsigned u; } x; x.p = v; return x.u;
}

__device__ __forceinline__ h8 h8w(unsigned a, unsigned b, unsigned c, unsigned d)
{
    union { unsigned u[4]; h8 h; } x;
    x.u[0] = a; x.u[1] = b; x.u[2] = c; x.u[3] = d;
    return x.h;
}

__device__ __forceinline__ f16x ld16(const float* p)
{
    const f4* q = (const f4*)p;
    f4 a = q[0], b = q[1], c = q[2], d = q[3];
    f16x r;
#pragma unroll
    for (int i = 0; i < 4; ++i) { r[i] = a[i]; r[4+i] = b[i]; r[8+i] = c[i]; r[12+i] = d[i]; }
    return r;
}

__device__ __forceinline__ float hsum16(const f16x& v)
{
    float a0 = (v[0]+v[1])+(v[2]+v[3]);
    float a1 = (v[4]+v[5])+(v[6]+v[7]);
    float a2 = (v[8]+v[9])+(v[10]+v[11]);
    float a3 = (v[12]+v[13])+(v[14]+v[15]);
    return (a0+a1)+(a2+a3);
}

__device__ __forceinline__ float dot16(const f16x& a, const f16x& b)
{
    float d0 = a[0]*b[0], d1 = a[1]*b[1], d2 = a[2]*b[2], d3 = a[3]*b[3];
#pragma unroll
    for (int i = 4; i < 16; i += 4) {
        d0 = fmaf(a[i+0], b[i+0], d0);
        d1 = fmaf(a[i+1], b[i+1], d1);
        d2 = fmaf(a[i+2], b[i+2], d2);
        d3 = fmaf(a[i+3], b[i+3], d3);
    }
    return (d0+d1)+(d2+d3);
}

// per-tile feature builder (R20's in-register scheme): one doubling chain per
// lane (hb=0 cost, hb=1 angle), 4 shfl_xor(32) to exchange packed words.
__device__ __forceinline__ void feat_frags(float xc, float2 ci, float2 cj, int hb,
                                           float sc0, float sc1, h8& fb0, h8& fb1)
{
    const float dx = ci.x - cj.x, dy = ci.y - cj.y;
    const float rr = dx*dx + dy*dy;
    const float rinv = __builtin_amdgcn_rsqf(rr);
    // fast atan2(dy,dx): minimax deg-11, |err|~1e-5 (f16 feature ulp ~1e-3)
    const float ax = fabsf(dx), ay = fabsf(dy);
    const float mx = fmaxf(ax, ay), mn = fminf(ax, ay);
    const float t = mn * __builtin_amdgcn_rcpf(mx);
    const float t2 = t*t;
    float pa = fmaf(t2, -0.0117212f, 0.05265332f);
    pa = fmaf(t2, pa, -0.11643287f);
    pa = fmaf(t2, pa, 0.19354346f);
    pa = fmaf(t2, pa, -0.33262347f);
    pa = fmaf(t2, pa, 0.99997726f);
    float a = t * pa;
    a = (ay > ax) ? 1.57079632679f - a : a;
    a = (dx < 0.f) ? 3.14159265359f - a : a;
    a = __int_as_float(__float_as_int(a) | (__float_as_int(dy) & 0x80000000));
    const bool ok = rr > 0.f;                  // diagonal (i==j): angle=0
    const float ang = ok ? a : 0.f;
    const float snA = ok ? dy*rinv : 0.f;      // sin(atan2) exact
    const float csA = ok ? dx*rinv : 1.f;      // cos(atan2) exact
    const float xv  = hb ? ang : xc;
    const float sn1 = hb ? snA : __sinf(xc);
    const float cs1 = hb ? csA : __cosf(xc);
    const float sE  = hb ? sc1 : sc0;
    const float sn2 = 2.f*sn1*cs1, cs2 = fmaf(-2.f*sn1, sn1, 1.f);
    const float sn4 = 2.f*sn2*cs2, cs4 = fmaf(-2.f*sn2, sn2, 1.f);
    const float sn8 = 2.f*sn4*cs4, cs8 = fmaf(-2.f*sn4, sn4, 1.f);
    const unsigned u0 = pu(__builtin_amdgcn_cvt_pkrtz(xv*sE,  sn1*sE));
    const unsigned u1 = pu(__builtin_amdgcn_cvt_pkrtz(cs1*sE, sn2*sE));
    const unsigned u2 = pu(__builtin_amdgcn_cvt_pkrtz(cs2*sE, sn4*sE));
    const unsigned u3 = pu(__builtin_amdgcn_cvt_pkrtz(cs4*sE, sn8*sE));
    const unsigned u4 = pu(__builtin_amdgcn_cvt_pkrtz(cs8*sE, 1.0f));  // feats 8,9 (9 = bias-1)
    const unsigned sel0 = hb ? u0 : u4;
    const unsigned rw0 = __shfl_xor((int)sel0, 32);
    const unsigned rw1 = __shfl_xor((int)u1, 32);
    const unsigned rw2 = __shfl_xor((int)u2, 32);
    const unsigned rw3 = __shfl_xor((int)u3, 32);
    fb0 = hb ? h8w(rw0, 0, 0, 0) : h8w(u0, u1, u2, u3);    // cost enc
    fb1 = hb ? h8w(u4, 0, 0, 0) : h8w(rw0, rw1, rw2, rw3); // angle enc
}

// R21 = R20 restructured to ONE 64-pair pass per wave (tiles A/B share every
// LDS read): per-pair ds_read_b128 count halves (72 per 64 pairs vs 72 per 32).
// Rationale: R18->R20 flat at ~44us with occupancy up = CU-shared LDS pipe is
// the bottleneck (72 reads x 12cy x 64 tiles/CU ~ 23us). Cost: both tiles' E
// live through L2 (~200 regs) -> bounds(256,2), 2 waves/SIMD (LDS/VALU bound,
// TLP not needed). Grid: 2048 blocks x 4 waves x 64 pairs = NPAIR, loop gone.
__global__ __launch_bounds__(256, 2) void fused_kernel(
    const float* __restrict__ coords, const float* __restrict__ cost,
    const float* __restrict__ lscale, const float* __restrict__ bg2,
    const float* __restrict__ gt, const float* __restrict__ bo,
    float* __restrict__ out)
{
    __shared__ __align__(16) char smem[32768 + 1280];
    const int tid = threadIdx.x;
    const int wave = tid >> 6, lane = tid & 63;
    const int pr = lane & 31, hb = lane >> 5;

    h8* wpool = (h8*)smem;                    // [0,1024) W2' frags, [1024,2048) Wg1 frags
    for (int z = tid; z < 2048; z += 256) wpool[z] = g_frag[128 + z];
    float* cpool = (float*)(smem + 32768);    // 320 epilogue consts
    for (int z = tid; z < 320; z += 256) cpool[z] = g_cst[z];
    __syncthreads();

    // W1^T A-frags, register-resident (8 VGPRs)
    h8 w1a0 = g_frag[lane], w1a1 = g_frag[64 + lane];

    const float dlgb = bg2[1] - bg2[0];
    const float sc0 = __expf(lscale[0]), sc1 = __expf(lscale[1]);
    const float invT2 = __expf(-gt[0]) * LOG2E;
    const float outc = g_cc[0] + bo[0], C1 = g_cc[1];

    const int wgid = blockIdx.x*4 + wave;      // 0..8191
    const int p0 = wgid*64;                    // tiles: A=[p0,p0+32), B=[p0+32,p0+64)
    const int bb = p0 >> 16, ii = (p0 >> 8) & 255, j0 = p0 & 255;  // j0 in {0,64,128,192}

    const float2* cb2 = (const float2*)(coords + (bb << 9));
    const float2 ci = cb2[ii];
    const float xcA = cost[p0 + pr];
    const float xcB = cost[p0 + 32 + pr];
    const float2 cjA = cb2[j0 + pr];
    const float2 cjB = cb2[j0 + 32 + pr];

    h8 fbA0, fbA1, fbB0, fbB1;
    feat_frags(xcA, ci, cjA, hb, sc0, sc1, fbA0, fbA1);
    feat_frags(xcB, ci, cjB, hb, sc0, sc1, fbB0, fbB1);

    const f16x z16 = {0.f,0.f,0.f,0.f,0.f,0.f,0.f,0.f,0.f,0.f,0.f,0.f,0.f,0.f,0.f,0.f};
    // launder pool pointers: keep gate1/L2 reads from being hoisted across phases
    int wofs = 0; asm volatile("" : "+s"(wofs));
    const h8* wp = wpool + wofs;
    const float* cstl = cpool + wofs;

    // ---- enc0: L1 + silu for A and B ----
    f16x HA0 = MFMA(w1a0, fbA0, z16);
    f16x HA1 = MFMA(w1a1, fbA0, z16);
    f16x HB0 = MFMA(w1a0, fbB0, z16);
    f16x HB1 = MFMA(w1a1, fbB0, z16);
    HA0 = xsig16(HA0); HA1 = xsig16(HA1); HB0 = xsig16(HB0); HB1 = xsig16(HB1);
    h8 hA0 = pk8<0>(HA0), hA1 = pk8<8>(HA0), hA2 = pk8<0>(HA1), hA3 = pk8<8>(HA1);
    h8 hB0 = pk8<0>(HB0), hB1 = pk8<8>(HB0), hB2 = pk8<0>(HB1), hB3 = pk8<8>(HB1);
    // ---- L2 enc0: 8 shared frag reads -> 16 MFMAs ----
    h8 wv;
    const f16x i00 = ld16(cstl + 16*hb);
    const f16x i01 = ld16(cstl + 32 + 16*hb);
    wv = wp[0*64+lane]; f16x EA00 = MFMA(wv, hA0, i00); f16x EB00 = MFMA(wv, hB0, i00);
    wv = wp[1*64+lane]; EA00 = MFMA(wv, hA1, EA00); EB00 = MFMA(wv, hB1, EB00);
    wv = wp[2*64+lane]; EA00 = MFMA(wv, hA2, EA00); EB00 = MFMA(wv, hB2, EB00);
    wv = wp[3*64+lane]; EA00 = MFMA(wv, hA3, EA00); EB00 = MFMA(wv, hB3, EB00);
    wv = wp[4*64+lane]; f16x EA01 = MFMA(wv, hA0, i01); f16x EB01 = MFMA(wv, hB0, i01);
    wv = wp[5*64+lane]; EA01 = MFMA(wv, hA1, EA01); EB01 = MFMA(wv, hB1, EB01);
    wv = wp[6*64+lane]; EA01 = MFMA(wv, hA2, EA01); EB01 = MFMA(wv, hB2, EB01);
    wv = wp[7*64+lane]; EA01 = MFMA(wv, hA3, EA01); EB01 = MFMA(wv, hB3, EB01);
    // ---- enc1: L1 + silu for A and B (reuses h-frag registers) ----
    HA0 = MFMA(w1a0, fbA1, z16);
    HA1 = MFMA(w1a1, fbA1, z16);
    HB0 = MFMA(w1a0, fbB1, z16);
    HB1 = MFMA(w1a1, fbB1, z16);
    HA0 = xsig16(HA0); HA1 = xsig16(HA1); HB0 = xsig16(HB0); HB1 = xsig16(HB1);
    hA0 = pk8<0>(HA0); hA1 = pk8<8>(HA0); hA2 = pk8<0>(HA1); hA3 = pk8<8>(HA1);
    hB0 = pk8<0>(HB0); hB1 = pk8<8>(HB0); hB2 = pk8<0>(HB1); hB3 = pk8<8>(HB1);
    // ---- L2 enc1 ----
    const f16x i10 = ld16(cstl + 64 + 16*hb);
    const f16x i11 = ld16(cstl + 96 + 16*hb);
    wv = wp[ 8*64+lane]; f16x EA10 = MFMA(wv, hA0, i10); f16x EB10 = MFMA(wv, hB0, i10);
    wv = wp[ 9*64+lane]; EA10 = MFMA(wv, hA1, EA10); EB10 = MFMA(wv, hB1, EB10);
    wv = wp[10*64+lane]; EA10 = MFMA(wv, hA2, EA10); EB10 = MFMA(wv, hB2, EB10);
    wv = wp[11*64+lane]; EA10 = MFMA(wv, hA3, EA10); EB10 = MFMA(wv, hB3, EB10);
    wv = wp[12*64+lane]; f16x EA11 = MFMA(wv, hA0, i11); f16x EB11 = MFMA(wv, hB0, i11);
    wv = wp[13*64+lane]; EA11 = MFMA(wv, hA1, EA11); EB11 = MFMA(wv, hB1, EB11);
    wv = wp[14*64+lane]; EA11 = MFMA(wv, hA2, EA11); EB11 = MFMA(wv, hB2, EB11);
    wv = wp[15*64+lane]; EA11 = MFMA(wv, hA3, EA11); EB11 = MFMA(wv, hB3, EB11);
    // ---- LN/head partials over this lane's 32 channels (shared gw read) ----
    const f16x gw0 = ld16(cstl + 256 + 16*hb);
    const f16x gw1 = ld16(cstl + 288 + 16*hb);
    const float A0a = hsum16(EA00) + hsum16(EA01);
    const float A1a = hsum16(EA10) + hsum16(EA11);
    const float D0a = dot16(EA00, gw0) + dot16(EA01, gw1);
    const float D1a = dot16(EA10, gw0) + dot16(EA11, gw1);
    const float Q0a = dot16(EA00, EA00) + dot16(EA01, EA01);
    const float QXa = dot16(EA00, EA10) + dot16(EA01, EA11);
    const float Q2a = dot16(EA10, EA10) + dot16(EA11, EA11);
    const float A0b = hsum16(EB00) + hsum16(EB01);
    const float A1b = hsum16(EB10) + hsum16(EB11);
    const float D0b = dot16(EB00, gw0) + dot16(EB01, gw1);
    const float D1b = dot16(EB10, gw0) + dot16(EB11, gw1);
    const float Q0b = dot16(EB00, EB00) + dot16(EB01, EB01);
    const float QXb = dot16(EB00, EB10) + dot16(EB01, EB11);
    const float Q2b = dot16(EB10, EB10) + dot16(EB11, EB11);
    // convert E -> f16 gate-input frags; all f32 E regs die here
    const h8 eA0 = pk8<0>(EA00), eA1 = pk8<8>(EA00), eA2 = pk8<0>(EA01), eA3 = pk8<8>(EA01);
    const h8 eA4 = pk8<0>(EA10), eA5 = pk8<8>(EA10), eA6 = pk8<0>(EA11), eA7 = pk8<8>(EA11);
    const h8 eB0 = pk8<0>(EB00), eB1 = pk8<8>(EB00), eB2 = pk8<0>(EB01), eB3 = pk8<8>(EB01);
    const h8 eB4 = pk8<0>(EB10), eB5 = pk8<8>(EB10), eB6 = pk8<0>(EB11), eB7 = pk8<8>(EB11);
    // ---- gate1: K=128 = 16 shared frag reads -> 32 MFMAs ----
    int wofs2 = 0; asm volatile("" : "+s"(wofs2));
    const h8* wq = wpool + 1024 + wofs2;
    const float* cst2 = cpool + wofs2;
    const f16x ig0 = ld16(cst2 + 128 + 16*hb);
    const f16x ig1 = ld16(cst2 + 160 + 16*hb);
    wv = wq[ 0*64+lane]; f16x GA0 = MFMA(wv, eA0, ig0); f16x GB0 = MFMA(wv, eB0, ig0);
    wv = wq[ 1*64+lane]; GA0 = MFMA(wv, eA1, GA0); GB0 = MFMA(wv, eB1, GB0);
    wv = wq[ 2*64+lane]; GA0 = MFMA(wv, eA2, GA0); GB0 = MFMA(wv, eB2, GB0);
    wv = wq[ 3*64+lane]; GA0 = MFMA(wv, eA3, GA0); GB0 = MFMA(wv, eB3, GB0);
    wv = wq[ 4*64+lane]; GA0 = MFMA(wv, eA4, GA0); GB0 = MFMA(wv, eB4, GB0);
    wv = wq[ 5*64+lane]; GA0 = MFMA(wv, eA5, GA0); GB0 = MFMA(wv, eB5, GB0);
    wv = wq[ 6*64+lane]; GA0 = MFMA(wv, eA6, GA0); GB0 = MFMA(wv, eB6, GB0);
    wv = wq[ 7*64+lane]; GA0 = MFMA(wv, eA7, GA0); GB0 = MFMA(wv, eB7, GB0);
    wv = wq[ 8*64+lane]; f16x GA1 = MFMA(wv, eA0, ig1); f16x GB1 = MFMA(wv, eB0, ig1);
    wv = wq[ 9*64+lane]; GA1 = MFMA(wv, eA1, GA1); GB1 = MFMA(wv, eB1, GB1);
    wv = wq[10*64+lane]; GA1 = MFMA(wv, eA2, GA1); GB1 = MFMA(wv, eB2, GB1);
    wv = wq[11*64+lane]; GA1 = MFMA(wv, eA3, GA1); GB1 = MFMA(wv, eB3, GB1);
    wv = wq[12*64+lane]; GA1 = MFMA(wv, eA4, GA1); GB1 = MFMA(wv, eB4, GB1);
    wv = wq[13*64+lane]; GA1 = MFMA(wv, eA5, GA1); GB1 = MFMA(wv, eB5, GB1);
    wv = wq[14*64+lane]; GA1 = MFMA(wv, eA6, GA1); GB1 = MFMA(wv, eB6, GB1);
    wv = wq[15*64+lane]; GA1 = MFMA(wv, eA7, GA1); GB1 = MFMA(wv, eB7, GB1);
    GA0 = xsig16(GA0); GA1 = xsig16(GA1); GB0 = xsig16(GB0); GB1 = xsig16(GB1);
    // ---- gate2 (VALU): logit diff; in-lane 32 + 1 shfl (shared wd read) ----
    const f16x wd0 = ld16(cst2 + 192 + 16*hb);
    const f16x wd1 = ld16(cst2 + 224 + 16*hb);
    float partA = dot16(GA0, wd0) + dot16(GA1, wd1);
    float partB = dot16(GB0, wd0) + dot16(GB1, wd1);
    partA += __shfl_xor(partA, 32);
    partB += __shfl_xor(partB, 32);
    const float w1A = __builtin_amdgcn_rcpf(1.f + __builtin_amdgcn_exp2f(-(partA + dlgb)*invT2));
    const float w1B = __builtin_amdgcn_rcpf(1.f + __builtin_amdgcn_exp2f(-(partB + dlgb)*invT2));
    // ---- recombine partials: fu = (1-w)E0 + wE1 (never materialized) ----
    const float uA = 1.f - w1A, uB = 1.f - w1B;
    float svA = fmaf(w1A, A1a - A0a, A0a);
    float dtA = fmaf(w1A, D1a - D0a, D0a);
    float sqA = uA*uA*Q0a + 2.f*uA*w1A*QXa + w1A*w1A*Q2a;
    float svB = fmaf(w1B, A1b - A0b, A0b);
    float dtB = fmaf(w1B, D1b - D0b, D0b);
    float sqB = uB*uB*Q0b + 2.f*uB*w1B*QXb + w1B*w1B*Q2b;
    svA += __shfl_xor(svA, 32); sqA += __shfl_xor(sqA, 32); dtA += __shfl_xor(dtA, 32);
    svB += __shfl_xor(svB, 32); sqB += __shfl_xor(sqB, 32); dtB += __shfl_xor(dtB, 32);
    const float muA = svA * (1.f/64.f);
    const float vvA = sqA * (1.f/64.f) - muA*muA;
    const float rsA = __builtin_amdgcn_rsqf(vvA + 1e-5f);
    const float oA = fmaf(rsA, dtA - muA*C1, outc);
    const float muB = svB * (1.f/64.f);
    const float vvB = sqB * (1.f/64.f) - muB*muB;
    const float rsB = __builtin_amdgcn_rsqf(vvB + 1e-5f);
    const float oB = fmaf(rsB, dtB - muB*C1, outc);
    // 64 consecutive floats, fully coalesced
    out[p0 + (hb ? 32 : 0) + pr] = hb ? oB : oA;
}

extern "C" void kernel_launch(void* const* d_in, const int* in_sizes, int n_in,
                              void* d_out, int out_size, void* d_ws, size_t ws_size,
                              hipStream_t stream)
{
    const float* coords = (const float*)d_in[0];
    const float* cost   = (const float*)d_in[1];
    const float* lscale = (const float*)d_in[2];
    const float* W1     = (const float*)d_in[3];
    const float* b1     = (const float*)d_in[4];
    const float* W2     = (const float*)d_in[5];
    const float* b2     = (const float*)d_in[6];
    const float* fg     = (const float*)d_in[7];
    const float* fb     = (const float*)d_in[8];
    const float* Wg1    = (const float*)d_in[9];
    const float* bg1    = (const float*)d_in[10];
    const float* Wg2    = (const float*)d_in[11];
    const float* bg2    = (const float*)d_in[12];
    const float* gt     = (const float*)d_in[13];
    const float* lng    = (const float*)d_in[14];
    const float* lnb    = (const float*)d_in[15];
    const float* Wo     = (const float*)d_in[16];
    const float* bo     = (const float*)d_in[17];
    float* out = (float*)d_out;

    prep_kernel<<<20, 256, 0, stream>>>(W1, b1, W2, b2, fg, fb, Wg1, bg1, Wg2, lng, lnb, Wo);
    fused_kernel<<<BLOCKS, 256, 0, stream>>>(coords, cost, lscale, bg2, gt, bo, out);
}

// Round 8
// 128.054 us; speedup vs baseline: 1.5478x; 1.5478x over previous
//
#include <hip/hip_runtime.h>
#include <math.h>

typedef _Float16 h4  __attribute__((ext_vector_type(4)));
typedef _Float16 h8  __attribute__((ext_vector_type(8)));
typedef __fp16   p2  __attribute__((ext_vector_type(2)));   // cvt_pkrtz result type
typedef float    f4  __attribute__((ext_vector_type(4)));
typedef float    f16x __attribute__((ext_vector_type(16)));

#define NPAIR (8*256*256)
#define NTILE32 (NPAIR/32)        // 16384 tiles of 32 pairs
#define BLOCKS 2048
#define ITERS (NTILE32/(BLOCKS*4))  // 2 tiles per wave

// 32x32x16 f16 MFMA (gfx950): C/D: col=lane&31, row=(reg&3)+8*(reg>>2)+4*(lane>>5)
// A/B (verified R18 on HW): m/n=lane&31, k=8*(lane>>5)+j
#define MFMA(a,b,c) __builtin_amdgcn_mfma_f32_32x32x16_f16((a),(b),(c),0,0,0)

#define LOG2E 1.44269504088896340736f
#define LN2   0.69314718055994530942f

// Physical->logical channel permutation for 64-wide layers built from two 32x32
// C/D tiles: physical P = 32*mt + (g&3)+8*(g>>2)+4*hi  holds logical channel
// kappa = 32*mt + 16*(g>>3) + 8*hi + (g&7).  With B-frag chunk c built as
// pk8(C[mt=c>>1] regs 8*(c&1)..+7), slot (c,hi,j) then holds logical 16c+8hi+j
// == the MFMA k-index -> layers chain in-register with identity k-axis.
__device__ __forceinline__ int pi64(int P)
{
    int mt = P >> 5, r = P & 31;
    int hi = (r >> 2) & 1;
    int g  = (r & 3) + 4*(r >> 3);
    return 32*mt + 16*(g >> 3) + 8*hi + (g & 7);
}

// A-fragment pool (h8 units):
// [0,128)      W1^T  frags [mt][lane]: elem j: k=8*(lane>>5)+j;
//              k<9 -> W1[k][pi(32mt+(lane&31))]*log2e; k==9 -> b1*log2e; else 0
// [128,1152)   W2'^T frags [(enc*2+mt)*4+c][lane]: k=16c+8*(lane>>5)+j;
//              val = W2[k][P]*fg[enc][P]*ln2, P=pi(32mt+(lane&31))
// [1152,2176)  Wg1^T frags [mt*8+cc][lane]: in=64*(cc>>2)+16*(cc&3)+8*(lane>>5)+j;
//              val = Wg1[in][P]*log2e
__device__ h8 g_frag[2176];
// Epilogue consts in C/D order: flat = base + mt*32 + hi*16 + g:
// [0,128) E-init (enc major)  [128,192) bg1*log2e  [192,256) (Wg2[1]-Wg2[0])*ln2
// [256,320) ln_g*Wo
__device__ float g_cst[320];
__device__ float g_cc[2];         // C0 = sum ln_b*Wo, C1 = sum ln_g*Wo

__global__ void prep_kernel(const float* __restrict__ W1, const float* __restrict__ b1,
                            const float* __restrict__ W2, const float* __restrict__ b2,
                            const float* __restrict__ fgam, const float* __restrict__ fbet,
                            const float* __restrict__ Wg1, const float* __restrict__ bg1,
                            const float* __restrict__ Wg2,
                            const float* __restrict__ ln_g, const float* __restrict__ ln_b,
                            const float* __restrict__ Wo)
{
    int idx = blockIdx.x * 256 + threadIdx.x;
    if (idx < 2176) {
        h8 v;
        if (idx < 128) {
            int mt = idx >> 6, L = idx & 63;
            int hi = L >> 5, m = L & 31;
            int P = pi64(32*mt + m);
#pragma unroll
            for (int j = 0; j < 8; ++j) {
                int k = 8*hi + j;
                float x = (k < 9) ? W1[k*64 + P] : (k == 9 ? b1[P] : 0.f);
                v[j] = (_Float16)(x * LOG2E);
            }
        } else if (idx < 1152) {
            int z = idx - 128; int f = z >> 6, L = z & 63;
            int c = f & 3, mt = (f >> 2) & 1, enc = f >> 3;
            int hi = L >> 5, m = L & 31;
            int P = pi64(32*mt + m);
            float fgv = fgam[enc*64 + P] * LN2;
#pragma unroll
            for (int j = 0; j < 8; ++j) {
                int k = 16*c + 8*hi + j;
                v[j] = (_Float16)(W2[k*64 + P] * fgv);
            }
        } else {
            int z = idx - 1152; int f = z >> 6, L = z & 63;
            int cc = f & 7, mt = f >> 3;
            int hi = L >> 5, m = L & 31;
            int P = pi64(32*mt + m);
#pragma unroll
            for (int j = 0; j < 8; ++j) {
                int in = 64*(cc >> 2) + 16*(cc & 3) + 8*hi + j;
                v[j] = (_Float16)(Wg1[in*64 + P] * LOG2E);
            }
        }
        g_frag[idx] = v;
    } else if (idx >= 4352 && idx < 4416) {
        int k = idx - 4352;
        float c0 = ln_b[k]*Wo[k], c1 = ln_g[k]*Wo[k];
#pragma unroll
        for (int s = 1; s < 64; s <<= 1) {
            c0 += __shfl_xor(c0, s);
            c1 += __shfl_xor(c1, s);
        }
        if (k == 0) { g_cc[0] = c0; g_cc[1] = c1; }
    } else if (idx >= 4608 && idx < 4928) {
        int c = idx - 4608;
        float v;
        if (c < 128) {
            int enc = c >> 6, w = c & 63;
            int mt = w >> 5, hi = (w >> 4) & 1, g = w & 15;
            int P = pi64(32*mt + (g & 3) + 8*(g >> 2) + 4*hi);
            v = fmaf(b2[P], fgam[enc*64 + P], fbet[enc*64 + P]);
        } else if (c < 192) {
            int w = c - 128, mt = w >> 5, hi = (w >> 4) & 1, g = w & 15;
            int P = pi64(32*mt + (g & 3) + 8*(g >> 2) + 4*hi);
            v = bg1[P] * LOG2E;
        } else if (c < 256) {
            int w = c - 192, mt = w >> 5, hi = (w >> 4) & 1, g = w & 15;
            int P = pi64(32*mt + (g & 3) + 8*(g >> 2) + 4*hi);
            v = (Wg2[2*P+1] - Wg2[2*P]) * LN2;
        } else {
            int w = c - 256, mt = w >> 5, hi = (w >> 4) & 1, g = w & 15;
            int P = pi64(32*mt + (g & 3) + 8*(g >> 2) + 4*hi);
            v = ln_g[P] * Wo[P];
        }
        g_cst[c] = v;
    }
}

// x' = x*log2e (folded into weights): x'/(1+2^-x') = log2e*silu(x); trailing ln2
// folded into the consumer. 2 trans + 2 VALU per element.
__device__ __forceinline__ f16x xsig16(f16x v)
{
#pragma unroll
    for (int i = 0; i < 16; ++i)
        v[i] = v[i] * __builtin_amdgcn_rcpf(1.f + __builtin_amdgcn_exp2f(-v[i]));
    return v;
}

template<int B>
__device__ __forceinline__ h8 pk8(const f16x& v)   // C/D regs B..B+7 -> h8 B-frag
{
    p2 a = __builtin_amdgcn_cvt_pkrtz(v[B+0], v[B+1]);
    p2 b = __builtin_amdgcn_cvt_pkrtz(v[B+2], v[B+3]);
    p2 c = __builtin_amdgcn_cvt_pkrtz(v[B+4], v[B+5]);
    p2 d = __builtin_amdgcn_cvt_pkrtz(v[B+6], v[B+7]);
    h8 r;
    r[0]=a[0]; r[1]=a[1]; r[2]=b[0]; r[3]=b[1];
    r[4]=c[0]; r[5]=c[1]; r[6]=d[0]; r[7]=d[1];
    return r;
}

__device__ __forceinline__ unsigned pu(p2 v)
{
    union { p2 p; unsigned u; } x; x.p = v; return x.u;
}

__device__ __forceinline__ h8 h8w(unsigned a, unsigned b, unsigned c, unsigned d)
{
    union { unsigned u[4]; h8 h; } x;
    x.u[0] = a; x.u[1] = b; x.u[2] = c; x.u[3] = d;
    return x.h;
}

__device__ __forceinline__ f16x ld16(const float* p)
{
    const f4* q = (const f4*)p;
    f4 a = q[0], b = q[1], c = q[2], d = q[3];
    f16x r;
#pragma unroll
    for (int i = 0; i < 4; ++i) { r[i] = a[i]; r[4+i] = b[i]; r[8+i] = c[i]; r[12+i] = d[i]; }
    return r;
}

__device__ __forceinline__ float hsum16(const f16x& v)
{
    float a0 = (v[0]+v[1])+(v[2]+v[3]);
    float a1 = (v[4]+v[5])+(v[6]+v[7]);
    float a2 = (v[8]+v[9])+(v[10]+v[11]);
    float a3 = (v[12]+v[13])+(v[14]+v[15]);
    return (a0+a1)+(a2+a3);
}

__device__ __forceinline__ float dot16(const f16x& a, const f16x& b)
{
    float d0 = a[0]*b[0], d1 = a[1]*b[1], d2 = a[2]*b[2], d3 = a[3]*b[3];
#pragma unroll
    for (int i = 4; i < 16; i += 4) {
        d0 = fmaf(a[i+0], b[i+0], d0);
        d1 = fmaf(a[i+1], b[i+1], d1);
        d2 = fmaf(a[i+2], b[i+2], d2);
        d3 = fmaf(a[i+3], b[i+3], d3);
    }
    return (d0+d1)+(d2+d3);
}

// R24 = R20 (last passing, 44.2us fused) + ONE change: epilogue/C-init consts
// read from GLOBAL g_cst instead of LDS cpool. All 32 lanes of an hb-half read
// the same 64B line -> L1 broadcast on the idle VMEM pipe. LDS reads per tile:
// 72 -> 32 ds_read_b128 (-55%), attacking the CU-shared LDS pipe identified as
// the R18-R20 plateau cause (R21/R22/R23 restructure attempts failed; this is
// the zero-restructure version of the same fix). No other change vs R20.
__global__ __launch_bounds__(256, 4) void fused_kernel(
    const float* __restrict__ coords, const float* __restrict__ cost,
    const float* __restrict__ lscale, const float* __restrict__ bg2,
    const float* __restrict__ gt, const float* __restrict__ bo,
    float* __restrict__ out)
{
    __shared__ __align__(16) char smem[32768];
    const int tid = threadIdx.x;
    const int wave = tid >> 6, lane = tid & 63;
    const int pr = lane & 31, hb = lane >> 5;

    h8* wpool = (h8*)smem;                    // [0,1024) W2' frags, [1024,2048) Wg1 frags
    for (int z = tid; z < 2048; z += 256) wpool[z] = g_frag[128 + z];
    __syncthreads();

    // W1^T A-frags, register-resident (8 VGPRs)
    h8 w1a0 = g_frag[lane], w1a1 = g_frag[64 + lane];

    const float dlgb = bg2[1] - bg2[0];
    const float sc0 = __expf(lscale[0]), sc1 = __expf(lscale[1]);
    const float invT2 = __expf(-gt[0]) * LOG2E;
    const float outc = g_cc[0] + bo[0], C1 = g_cc[1];

    const int wgid = blockIdx.x*4 + wave;

    for (int it = 0; it < ITERS; ++it) {
        const int T = wgid + it*(BLOCKS*4);
        const int p0 = T*32;
        const int bb = p0 >> 16, ii = (p0 >> 8) & 255, j0 = p0 & 255;
        // ---- features: each lane computes BOTH encoders for pair pr ----
        const float xc = cost[p0 + pr];
        const float2* cb2 = (const float2*)(coords + (bb << 9));
        const float2 ci = cb2[ii];
        const float2 cj = cb2[j0 + pr];
        const float dx = ci.x - cj.x, dy = ci.y - cj.y;
        const float rr = dx*dx + dy*dy;
        const float rinv = __builtin_amdgcn_rsqf(rr);
        // fast atan2(dy,dx): minimax deg-11, |err|~1e-5 (f16 feature ulp ~1e-3)
        const float ax = fabsf(dx), ay = fabsf(dy);
        const float mx = fmaxf(ax, ay), mn = fminf(ax, ay);
        const float t = mn * __builtin_amdgcn_rcpf(mx);
        const float t2 = t*t;
        float pa = fmaf(t2, -0.0117212f, 0.05265332f);
        pa = fmaf(t2, pa, -0.11643287f);
        pa = fmaf(t2, pa, 0.19354346f);
        pa = fmaf(t2, pa, -0.33262347f);
        pa = fmaf(t2, pa, 0.99997726f);
        float a = t * pa;
        a = (ay > ax) ? 1.57079632679f - a : a;
        a = (dx < 0.f) ? 3.14159265359f - a : a;
        a = __int_as_float(__float_as_int(a) | (__float_as_int(dy) & 0x80000000));
        const bool ok = rr > 0.f;                  // diagonal (i==j): angle=0
        const float ang = ok ? a : 0.f;
        const float snA = ok ? dy*rinv : 0.f;      // sin(atan2) exact
        const float csA = ok ? dx*rinv : 1.f;      // cos(atan2) exact
        // select this lane's domain, run ONE doubling chain
        const float xv  = hb ? ang : xc;
        const float sn1 = hb ? snA : __sinf(xc);
        const float cs1 = hb ? csA : __cosf(xc);
        const float sE  = hb ? sc1 : sc0;
        const float sn2 = 2.f*sn1*cs1, cs2 = fmaf(-2.f*sn1, sn1, 1.f);
        const float sn4 = 2.f*sn2*cs2, cs4 = fmaf(-2.f*sn2, sn2, 1.f);
        const float sn8 = 2.f*sn4*cs4, cs8 = fmaf(-2.f*sn4, sn4, 1.f);
        const unsigned u0 = pu(__builtin_amdgcn_cvt_pkrtz(xv*sE,  sn1*sE));
        const unsigned u1 = pu(__builtin_amdgcn_cvt_pkrtz(cs1*sE, sn2*sE));
        const unsigned u2 = pu(__builtin_amdgcn_cvt_pkrtz(cs2*sE, sn4*sE));
        const unsigned u3 = pu(__builtin_amdgcn_cvt_pkrtz(cs4*sE, sn8*sE));
        const unsigned u4 = pu(__builtin_amdgcn_cvt_pkrtz(cs8*sE, 1.0f));  // feats 8,9 (9 = bias-1)
        // exchange across lane^32: slot0 carries w0 (angle->hb0) / w4 (cost->hb1)
        const unsigned sel0 = hb ? u0 : u4;
        const unsigned rw0 = __shfl_xor((int)sel0, 32);
        const unsigned rw1 = __shfl_xor((int)u1, 32);
        const unsigned rw2 = __shfl_xor((int)u2, 32);
        const unsigned rw3 = __shfl_xor((int)u3, 32);
        // B-frags: lane(n=pr,hb) elem j <-> feat k=8*hb+j
        const h8 fb0 = hb ? h8w(rw0, 0, 0, 0) : h8w(u0, u1, u2, u3);   // cost enc
        const h8 fb1 = hb ? h8w(u4, 0, 0, 0) : h8w(rw0, rw1, rw2, rw3); // angle enc
        // ---- L1: H' = (W1*log2e)^T @ feat^T, K=16 (10 feats + zero pad) ----
        const f16x z16 = {0.f,0.f,0.f,0.f,0.f,0.f,0.f,0.f,0.f,0.f,0.f,0.f,0.f,0.f,0.f,0.f};
        f16x H00 = MFMA(w1a0, fb0, z16);
        f16x H01 = MFMA(w1a1, fb0, z16);
        f16x H10 = MFMA(w1a0, fb1, z16);
        f16x H11 = MFMA(w1a1, fb1, z16);
        // launder pool pointers: block LICM from hoisting frags/consts into regs
        int wofs = 0; asm volatile("" : "+s"(wofs));
        const h8* wp = wpool + wofs;
        const float* cstl = g_cst + wofs;      // <- global, L1-broadcast (was LDS cpool)
        // ---- L2 enc0 ----
        H00 = xsig16(H00); H01 = xsig16(H01);
        h8 hf0 = pk8<0>(H00), hf1 = pk8<8>(H00), hf2 = pk8<0>(H01), hf3 = pk8<8>(H01);
        f16x E00 = ld16(cstl + 16*hb);
        f16x E01 = ld16(cstl + 32 + 16*hb);
        E00 = MFMA(wp[0*64+lane], hf0, E00);
        E00 = MFMA(wp[1*64+lane], hf1, E00);
        E00 = MFMA(wp[2*64+lane], hf2, E00);
        E00 = MFMA(wp[3*64+lane], hf3, E00);
        E01 = MFMA(wp[4*64+lane], hf0, E01);
        E01 = MFMA(wp[5*64+lane], hf1, E01);
        E01 = MFMA(wp[6*64+lane], hf2, E01);
        E01 = MFMA(wp[7*64+lane], hf3, E01);
        // ---- L2 enc1 ----
        H10 = xsig16(H10); H11 = xsig16(H11);
        hf0 = pk8<0>(H10); hf1 = pk8<8>(H10); hf2 = pk8<0>(H11); hf3 = pk8<8>(H11);
        f16x E10 = ld16(cstl + 64 + 16*hb);
        f16x E11 = ld16(cstl + 96 + 16*hb);
        E10 = MFMA(wp[ 8*64+lane], hf0, E10);
        E10 = MFMA(wp[ 9*64+lane], hf1, E10);
        E10 = MFMA(wp[10*64+lane], hf2, E10);
        E10 = MFMA(wp[11*64+lane], hf3, E10);
        E11 = MFMA(wp[12*64+lane], hf0, E11);
        E11 = MFMA(wp[13*64+lane], hf1, E11);
        E11 = MFMA(wp[14*64+lane], hf2, E11);
        E11 = MFMA(wp[15*64+lane], hf3, E11);
        // ---- LN/head partials over this lane's 32 channels (E still live) ----
        const f16x gw0 = ld16(cstl + 256 + 16*hb);
        const f16x gw1 = ld16(cstl + 288 + 16*hb);
        const float A0 = hsum16(E00) + hsum16(E01);
        const float A1 = hsum16(E10) + hsum16(E11);
        const float D0 = dot16(E00, gw0) + dot16(E01, gw1);
        const float D1 = dot16(E10, gw0) + dot16(E11, gw1);
        const float Q0 = dot16(E00, E00) + dot16(E01, E01);
        const float QX = dot16(E00, E10) + dot16(E01, E11);
        const float Q2 = dot16(E10, E10) + dot16(E11, E11);
        // convert E -> f16 gate-input frags; all 64 f32 E regs die here
        const h8 ef0 = pk8<0>(E00), ef1 = pk8<8>(E00), ef2 = pk8<0>(E01), ef3 = pk8<8>(E01);
        const h8 ef4 = pk8<0>(E10), ef5 = pk8<8>(E10), ef6 = pk8<0>(E11), ef7 = pk8<8>(E11);
        // ---- gate1: K=128 = enc0 chunks 0..3 then enc1 chunks 4..7 ----
        f16x G0 = ld16(cstl + 128 + 16*hb);
        f16x G1 = ld16(cstl + 160 + 16*hb);
        G0 = MFMA(wp[1024+ 0*64+lane], ef0, G0);
        G0 = MFMA(wp[1024+ 1*64+lane], ef1, G0);
        G0 = MFMA(wp[1024+ 2*64+lane], ef2, G0);
        G0 = MFMA(wp[1024+ 3*64+lane], ef3, G0);
        G0 = MFMA(wp[1024+ 4*64+lane], ef4, G0);
        G0 = MFMA(wp[1024+ 5*64+lane], ef5, G0);
        G0 = MFMA(wp[1024+ 6*64+lane], ef6, G0);
        G0 = MFMA(wp[1024+ 7*64+lane], ef7, G0);
        G1 = MFMA(wp[1024+ 8*64+lane], ef0, G1);
        G1 = MFMA(wp[1024+ 9*64+lane], ef1, G1);
        G1 = MFMA(wp[1024+10*64+lane], ef2, G1);
        G1 = MFMA(wp[1024+11*64+lane], ef3, G1);
        G1 = MFMA(wp[1024+12*64+lane], ef4, G1);
        G1 = MFMA(wp[1024+13*64+lane], ef5, G1);
        G1 = MFMA(wp[1024+14*64+lane], ef6, G1);
        G1 = MFMA(wp[1024+15*64+lane], ef7, G1);
        G0 = xsig16(G0); G1 = xsig16(G1);
        // ---- gate2 (VALU): logit diff; in-lane 32 + 1 shfl (hi-half) ----
        const f16x wd0 = ld16(cstl + 192 + 16*hb);
        const f16x wd1 = ld16(cstl + 224 + 16*hb);
        float part = dot16(G0, wd0) + dot16(G1, wd1);
        part += __shfl_xor(part, 32);
        const float w1v = __builtin_amdgcn_rcpf(1.f + __builtin_amdgcn_exp2f(-(part + dlgb)*invT2));
        // ---- recombine partials: fu = (1-w)E0 + wE1 (never materialized) ----
        const float uv = 1.f - w1v;
        float sv = fmaf(w1v, A1 - A0, A0);
        float dt = fmaf(w1v, D1 - D0, D0);
        float sq = uv*uv*Q0 + 2.f*uv*w1v*QX + w1v*w1v*Q2;
        sv += __shfl_xor(sv, 32);
        sq += __shfl_xor(sq, 32);
        dt += __shfl_xor(dt, 32);
        const float mu = sv * (1.f/64.f);
        const float vv = sq * (1.f/64.f) - mu*mu;
        const float rs = __builtin_amdgcn_rsqf(vv + 1e-5f);
        const float o = fmaf(rs, dt - mu*C1, outc);
        if (lane < 32) out[p0 + lane] = o;
    }
}

extern "C" void kernel_launch(void* const* d_in, const int* in_sizes, int n_in,
                              void* d_out, int out_size, void* d_ws, size_t ws_size,
                              hipStream_t stream)
{
    const float* coords = (const float*)d_in[0];
    const float* cost   = (const float*)d_in[1];
    const float* lscale = (const float*)d_in[2];
    const float* W1     = (const float*)d_in[3];
    const float* b1     = (const float*)d_in[4];
    const float* W2     = (const float*)d_in[5];
    const float* b2     = (const float*)d_in[6];
    const float* fg     = (const float*)d_in[7];
    const float* fb     = (const float*)d_in[8];
    const float* Wg1    = (const float*)d_in[9];
    const float* bg1    = (const float*)d_in[10];
    const float* Wg2    = (const float*)d_in[11];
    const float* bg2    = (const float*)d_in[12];
    const float* gt     = (const float*)d_in[13];
    const float* lng    = (const float*)d_in[14];
    const float* lnb    = (const float*)d_in[15];
    const float* Wo     = (const float*)d_in[16];
    const float* bo     = (const float*)d_in[17];
    float* out = (float*)d_out;

    prep_kernel<<<20, 256, 0, stream>>>(W1, b1, W2, b2, fg, fb, Wg1, bg1, Wg2, lng, lnb, Wo);
    fused_kernel<<<BLOCKS, 256, 0, stream>>>(coords, cost, lscale, bg2, gt, bo, out);
}

// Round 9
// 124.170 us; speedup vs baseline: 1.5962x; 1.0313x over previous
//
#include <hip/hip_runtime.h>
#include <math.h>

typedef _Float16 h4  __attribute__((ext_vector_type(4)));
typedef _Float16 h8  __attribute__((ext_vector_type(8)));
typedef __fp16   p2  __attribute__((ext_vector_type(2)));   // cvt_pkrtz / fdot2 operand type
typedef float    f4  __attribute__((ext_vector_type(4)));
typedef float    f16x __attribute__((ext_vector_type(16)));

#define NPAIR (8*256*256)
#define NTILE32 (NPAIR/32)        // 16384 tiles of 32 pairs
#define BLOCKS 2048
#define ITERS (NTILE32/(BLOCKS*4))  // 2 tiles per wave

// 32x32x16 f16 MFMA (gfx950): C/D: col=lane&31, row=(reg&3)+8*(reg>>2)+4*(lane>>5)
// A/B (verified R18 on HW): m/n=lane&31, k=8*(lane>>5)+j
#define MFMA(a,b,c) __builtin_amdgcn_mfma_f32_32x32x16_f16((a),(b),(c),0,0,0)

#define LOG2E 1.44269504088896340736f
#define LN2   0.69314718055994530942f

// Physical->logical channel permutation for 64-wide layers built from two 32x32
// C/D tiles: physical P = 32*mt + (g&3)+8*(g>>2)+4*hi  holds logical channel
// kappa = 32*mt + 16*(g>>3) + 8*hi + (g&7).  With B-frag chunk c built as
// pk8(C[mt=c>>1] regs 8*(c&1)..+7), slot (c,hi,j) then holds logical 16c+8hi+j
// == the MFMA k-index -> layers chain in-register with identity k-axis.
__device__ __forceinline__ int pi64(int P)
{
    int mt = P >> 5, r = P & 31;
    int hi = (r >> 2) & 1;
    int g  = (r & 3) + 4*(r >> 3);
    return 32*mt + 16*(g >> 3) + 8*hi + (g & 7);
}

// A-fragment pool (h8 units):
// [0,128)      W1^T  frags [mt][lane]: elem j: k=8*(lane>>5)+j;
//              k<9 -> W1[k][pi(32mt+(lane&31))]*log2e; k==9 -> b1*log2e; else 0
// [128,1152)   W2'^T frags [(enc*2+mt)*4+c][lane]: k=16c+8*(lane>>5)+j;
//              val = W2[k][P]*fg[enc][P]*ln2, P=pi(32mt+(lane&31))
// [1152,2176)  Wg1^T frags [mt*8+cc][lane]: in=64*(cc>>2)+16*(cc&3)+8*(lane>>5)+j;
//              val = Wg1[in][P]*log2e
__device__ h8 g_frag[2176];
// Epilogue consts in C/D order: flat = base + mt*32 + hi*16 + g:
// [0,128) E-init (enc major)  [128,192) bg1*log2e  [192,256) (Wg2[1]-Wg2[0])*ln2
// [256,320) ln_g*Wo
__device__ float g_cst[320];
__device__ float g_cc[2];         // C0 = sum ln_b*Wo, C1 = sum ln_g*Wo

__global__ void prep_kernel(const float* __restrict__ W1, const float* __restrict__ b1,
                            const float* __restrict__ W2, const float* __restrict__ b2,
                            const float* __restrict__ fgam, const float* __restrict__ fbet,
                            const float* __restrict__ Wg1, const float* __restrict__ bg1,
                            const float* __restrict__ Wg2,
                            const float* __restrict__ ln_g, const float* __restrict__ ln_b,
                            const float* __restrict__ Wo)
{
    int idx = blockIdx.x * 256 + threadIdx.x;
    if (idx < 2176) {
        h8 v;
        if (idx < 128) {
            int mt = idx >> 6, L = idx & 63;
            int hi = L >> 5, m = L & 31;
            int P = pi64(32*mt + m);
#pragma unroll
            for (int j = 0; j < 8; ++j) {
                int k = 8*hi + j;
                float x = (k < 9) ? W1[k*64 + P] : (k == 9 ? b1[P] : 0.f);
                v[j] = (_Float16)(x * LOG2E);
            }
        } else if (idx < 1152) {
            int z = idx - 128; int f = z >> 6, L = z & 63;
            int c = f & 3, mt = (f >> 2) & 1, enc = f >> 3;
            int hi = L >> 5, m = L & 31;
            int P = pi64(32*mt + m);
            float fgv = fgam[enc*64 + P] * LN2;
#pragma unroll
            for (int j = 0; j < 8; ++j) {
                int k = 16*c + 8*hi + j;
                v[j] = (_Float16)(W2[k*64 + P] * fgv);
            }
        } else {
            int z = idx - 1152; int f = z >> 6, L = z & 63;
            int cc = f & 7, mt = f >> 3;
            int hi = L >> 5, m = L & 31;
            int P = pi64(32*mt + m);
#pragma unroll
            for (int j = 0; j < 8; ++j) {
                int in = 64*(cc >> 2) + 16*(cc & 3) + 8*hi + j;
                v[j] = (_Float16)(Wg1[in*64 + P] * LOG2E);
            }
        }
        g_frag[idx] = v;
    } else if (idx >= 4352 && idx < 4416) {
        int k = idx - 4352;
        float c0 = ln_b[k]*Wo[k], c1 = ln_g[k]*Wo[k];
#pragma unroll
        for (int s = 1; s < 64; s <<= 1) {
            c0 += __shfl_xor(c0, s);
            c1 += __shfl_xor(c1, s);
        }
        if (k == 0) { g_cc[0] = c0; g_cc[1] = c1; }
    } else if (idx >= 4608 && idx < 4928) {
        int c = idx - 4608;
        float v;
        if (c < 128) {
            int enc = c >> 6, w = c & 63;
            int mt = w >> 5, hi = (w >> 4) & 1, g = w & 15;
            int P = pi64(32*mt + (g & 3) + 8*(g >> 2) + 4*hi);
            v = fmaf(b2[P], fgam[enc*64 + P], fbet[enc*64 + P]);
        } else if (c < 192) {
            int w = c - 128, mt = w >> 5, hi = (w >> 4) & 1, g = w & 15;
            int P = pi64(32*mt + (g & 3) + 8*(g >> 2) + 4*hi);
            v = bg1[P] * LOG2E;
        } else if (c < 256) {
            int w = c - 192, mt = w >> 5, hi = (w >> 4) & 1, g = w & 15;
            int P = pi64(32*mt + (g & 3) + 8*(g >> 2) + 4*hi);
            v = (Wg2[2*P+1] - Wg2[2*P]) * LN2;
        } else {
            int w = c - 256, mt = w >> 5, hi = (w >> 4) & 1, g = w & 15;
            int P = pi64(32*mt + (g & 3) + 8*(g >> 2) + 4*hi);
            v = ln_g[P] * Wo[P];
        }
        g_cst[c] = v;
    }
}

// x' = x*log2e (folded into weights): x'/(1+2^-x') = log2e*silu(x); trailing ln2
// folded into the consumer. 2 trans + 2 VALU per element.
__device__ __forceinline__ f16x xsig16(f16x v)
{
#pragma unroll
    for (int i = 0; i < 16; ++i)
        v[i] = v[i] * __builtin_amdgcn_rcpf(1.f + __builtin_amdgcn_exp2f(-v[i]));
    return v;
}

template<int B>
__device__ __forceinline__ h8 pk8(const f16x& v)   // C/D regs B..B+7 -> h8 B-frag
{
    p2 a = __builtin_amdgcn_cvt_pkrtz(v[B+0], v[B+1]);
    p2 b = __builtin_amdgcn_cvt_pkrtz(v[B+2], v[B+3]);
    p2 c = __builtin_amdgcn_cvt_pkrtz(v[B+4], v[B+5]);
    p2 d = __builtin_amdgcn_cvt_pkrtz(v[B+6], v[B+7]);
    h8 r;
    r[0]=a[0]; r[1]=a[1]; r[2]=b[0]; r[3]=b[1];
    r[4]=c[0]; r[5]=c[1]; r[6]=d[0]; r[7]=d[1];
    return r;
}

__device__ __forceinline__ unsigned pu(p2 v)
{
    union { p2 p; unsigned u; } x; x.p = v; return x.u;
}

__device__ __forceinline__ h8 h8w(unsigned a, unsigned b, unsigned c, unsigned d)
{
    union { unsigned u[4]; h8 h; } x;
    x.u[0] = a; x.u[1] = b; x.u[2] = c; x.u[3] = d;
    return x.h;
}

__device__ __forceinline__ f16x ld16(const float* p)
{
    const f4* q = (const f4*)p;
    f4 a = q[0], b = q[1], c = q[2], d = q[3];
    f16x r;
#pragma unroll
    for (int i = 0; i < 4; ++i) { r[i] = a[i]; r[4+i] = b[i]; r[8+i] = c[i]; r[12+i] = d[i]; }
    return r;
}

// 8-channel f16 dot via v_dot2_f32_f16 (2 ch/instr, f32 accumulate)
__device__ __forceinline__ float dot8h(h8 a, h8 b, float acc)
{
    union U { h8 v; p2 q[4]; } ua, ub;
    ua.v = a; ub.v = b;
#pragma unroll
    for (int i = 0; i < 4; ++i)
        acc = __builtin_amdgcn_fdot2(ua.q[i], ub.q[i], acc, false);
    return acc;
}

// R25 = R20 (44.2us, last good) + reductions moved to f16 fdot2:
// - R24 falsified the LDS-pipe theory (LDS reads -55% -> SLOWER); R19/R24 point
//   at issue+latency bound with only ~2.4 waves/SIMD. Limiter: unified regfile
//   (~64 arch + ~128 acc = 192/wave -> 2 waves/SIMD). The 64-reg f32 E block is
//   the biggest component, held live through the f32 partial reductions.
// - Fix: compute A/D/Q/QX and gate2 from the f16 e/g FRAGMENTS via
//   v_dot2_f32_f16 (gw/wd as f16 LDS tables in fragment order). f32 E dies
//   immediately after each L2 quadrant -> peak ~125 regs -> 4 waves/SIMD,
//   and ~144 fewer VALU instrs/tile. Consts stay in LDS (R24 revert).
__global__ __launch_bounds__(256, 4) void fused_kernel(
    const float* __restrict__ coords, const float* __restrict__ cost,
    const float* __restrict__ lscale, const float* __restrict__ bg2,
    const float* __restrict__ gt, const float* __restrict__ bo,
    float* __restrict__ out)
{
    __shared__ __align__(16) char smem[32768 + 1536];
    const int tid = threadIdx.x;
    const int wave = tid >> 6, lane = tid & 63;
    const int pr = lane & 31, hb = lane >> 5;

    h8* wpool = (h8*)smem;                    // [0,1024) W2' frags, [1024,2048) Wg1 frags
    for (int z = tid; z < 2048; z += 256) wpool[z] = g_frag[128 + z];
    float* cpool = (float*)(smem + 32768);    // [0,128) E-init, [128,192) G-init (f32)
    for (int z = tid; z < 192; z += 256) cpool[z] = g_cst[z];
    _Float16* gwh = (_Float16*)(smem + 32768 + 768);    // 128 halfs: ln_g*Wo, frag order
    _Float16* wdh = (_Float16*)(smem + 32768 + 1024);   // 64 halfs: (Wg2[1]-Wg2[0])*ln2
    for (int z = tid; z < 128; z += 256) gwh[z] = (_Float16)g_cst[256 + z];
    for (int z = tid; z < 64;  z += 256) wdh[z] = (_Float16)g_cst[192 + z];
    __syncthreads();

    // W1^T A-frags, register-resident (8 VGPRs)
    h8 w1a0 = g_frag[lane], w1a1 = g_frag[64 + lane];
    h8 onesh;
#pragma unroll
    for (int j = 0; j < 8; ++j) onesh[j] = (_Float16)1.f;

    const float dlgb = bg2[1] - bg2[0];
    const float sc0 = __expf(lscale[0]), sc1 = __expf(lscale[1]);
    const float invT2 = __expf(-gt[0]) * LOG2E;
    const float outc = g_cc[0] + bo[0], C1 = g_cc[1];

    const int wgid = blockIdx.x*4 + wave;

    for (int it = 0; it < ITERS; ++it) {
        const int T = wgid + it*(BLOCKS*4);
        const int p0 = T*32;
        const int bb = p0 >> 16, ii = (p0 >> 8) & 255, j0 = p0 & 255;
        // ---- features: each lane computes BOTH encoders for pair pr ----
        const float xc = cost[p0 + pr];
        const float2* cb2 = (const float2*)(coords + (bb << 9));
        const float2 ci = cb2[ii];
        const float2 cj = cb2[j0 + pr];
        const float dx = ci.x - cj.x, dy = ci.y - cj.y;
        const float rr = dx*dx + dy*dy;
        const float rinv = __builtin_amdgcn_rsqf(rr);
        // fast atan2(dy,dx): minimax deg-11, |err|~1e-5 (f16 feature ulp ~1e-3)
        const float ax = fabsf(dx), ay = fabsf(dy);
        const float mx = fmaxf(ax, ay), mn = fminf(ax, ay);
        const float t = mn * __builtin_amdgcn_rcpf(mx);
        const float t2 = t*t;
        float pa = fmaf(t2, -0.0117212f, 0.05265332f);
        pa = fmaf(t2, pa, -0.11643287f);
        pa = fmaf(t2, pa, 0.19354346f);
        pa = fmaf(t2, pa, -0.33262347f);
        pa = fmaf(t2, pa, 0.99997726f);
        float a = t * pa;
        a = (ay > ax) ? 1.57079632679f - a : a;
        a = (dx < 0.f) ? 3.14159265359f - a : a;
        a = __int_as_float(__float_as_int(a) | (__float_as_int(dy) & 0x80000000));
        const bool ok = rr > 0.f;                  // diagonal (i==j): angle=0
        const float ang = ok ? a : 0.f;
        const float snA = ok ? dy*rinv : 0.f;      // sin(atan2) exact
        const float csA = ok ? dx*rinv : 1.f;      // cos(atan2) exact
        // select this lane's domain, run ONE doubling chain
        const float xv  = hb ? ang : xc;
        const float sn1 = hb ? snA : __sinf(xc);
        const float cs1 = hb ? csA : __cosf(xc);
        const float sE  = hb ? sc1 : sc0;
        const float sn2 = 2.f*sn1*cs1, cs2 = fmaf(-2.f*sn1, sn1, 1.f);
        const float sn4 = 2.f*sn2*cs2, cs4 = fmaf(-2.f*sn2, sn2, 1.f);
        const float sn8 = 2.f*sn4*cs4, cs8 = fmaf(-2.f*sn4, sn4, 1.f);
        const unsigned u0 = pu(__builtin_amdgcn_cvt_pkrtz(xv*sE,  sn1*sE));
        const unsigned u1 = pu(__builtin_amdgcn_cvt_pkrtz(cs1*sE, sn2*sE));
        const unsigned u2 = pu(__builtin_amdgcn_cvt_pkrtz(cs2*sE, sn4*sE));
        const unsigned u3 = pu(__builtin_amdgcn_cvt_pkrtz(cs4*sE, sn8*sE));
        const unsigned u4 = pu(__builtin_amdgcn_cvt_pkrtz(cs8*sE, 1.0f));  // feats 8,9 (9 = bias-1)
        // exchange across lane^32: slot0 carries w0 (angle->hb0) / w4 (cost->hb1)
        const unsigned sel0 = hb ? u0 : u4;
        const unsigned rw0 = __shfl_xor((int)sel0, 32);
        const unsigned rw1 = __shfl_xor((int)u1, 32);
        const unsigned rw2 = __shfl_xor((int)u2, 32);
        const unsigned rw3 = __shfl_xor((int)u3, 32);
        // B-frags: lane(n=pr,hb) elem j <-> feat k=8*hb+j
        const h8 fb0 = hb ? h8w(rw0, 0, 0, 0) : h8w(u0, u1, u2, u3);   // cost enc
        const h8 fb1 = hb ? h8w(u4, 0, 0, 0) : h8w(rw0, rw1, rw2, rw3); // angle enc
        // ---- L1: H' = (W1*log2e)^T @ feat^T, K=16 (10 feats + zero pad) ----
        const f16x z16 = {0.f,0.f,0.f,0.f,0.f,0.f,0.f,0.f,0.f,0.f,0.f,0.f,0.f,0.f,0.f,0.f};
        f16x H00 = MFMA(w1a0, fb0, z16);
        f16x H01 = MFMA(w1a1, fb0, z16);
        f16x H10 = MFMA(w1a0, fb1, z16);
        f16x H11 = MFMA(w1a1, fb1, z16);
        // launder pool pointers: block LICM from hoisting frags/consts into regs
        int wofs = 0; asm volatile("" : "+s"(wofs));
        const h8* wp = wpool + wofs;
        const float* cstl = cpool + wofs;
        const h8* gwf = (const h8*)gwh + wofs;
        const h8* wdf = (const h8*)wdh + wofs;
        // f16 gw frags (shared by both encoders' D partials)
        const h8 gw00 = gwf[2*hb], gw01 = gwf[2*hb+1];
        const h8 gw10 = gwf[4+2*hb], gw11 = gwf[4+2*hb+1];
        // ---- L2 enc0 ----
        H00 = xsig16(H00); H01 = xsig16(H01);
        h8 hf0 = pk8<0>(H00), hf1 = pk8<8>(H00), hf2 = pk8<0>(H01), hf3 = pk8<8>(H01);
        f16x E00 = ld16(cstl + 16*hb);
        f16x E01 = ld16(cstl + 32 + 16*hb);
        E00 = MFMA(wp[0*64+lane], hf0, E00);
        E00 = MFMA(wp[1*64+lane], hf1, E00);
        E00 = MFMA(wp[2*64+lane], hf2, E00);
        E00 = MFMA(wp[3*64+lane], hf3, E00);
        E01 = MFMA(wp[4*64+lane], hf0, E01);
        E01 = MFMA(wp[5*64+lane], hf1, E01);
        E01 = MFMA(wp[6*64+lane], hf2, E01);
        E01 = MFMA(wp[7*64+lane], hf3, E01);
        // e-frags for enc0; f32 E00/E01 die right here (occupancy lever)
        const h8 ef0 = pk8<0>(E00), ef1 = pk8<8>(E00), ef2 = pk8<0>(E01), ef3 = pk8<8>(E01);
        // enc0 partials from f16 frags (fdot2; ones-dot is exact)
        float A0 = dot8h(ef1, onesh, dot8h(ef0, onesh, 0.f))
                 + dot8h(ef3, onesh, dot8h(ef2, onesh, 0.f));
        float D0 = dot8h(ef1, gw01, dot8h(ef0, gw00, 0.f))
                 + dot8h(ef3, gw11, dot8h(ef2, gw10, 0.f));
        float Q0 = dot8h(ef1, ef1, dot8h(ef0, ef0, 0.f))
                 + dot8h(ef3, ef3, dot8h(ef2, ef2, 0.f));
        // ---- L2 enc1 ----
        H10 = xsig16(H10); H11 = xsig16(H11);
        hf0 = pk8<0>(H10); hf1 = pk8<8>(H10); hf2 = pk8<0>(H11); hf3 = pk8<8>(H11);
        f16x E10 = ld16(cstl + 64 + 16*hb);
        f16x E11 = ld16(cstl + 96 + 16*hb);
        E10 = MFMA(wp[ 8*64+lane], hf0, E10);
        E10 = MFMA(wp[ 9*64+lane], hf1, E10);
        E10 = MFMA(wp[10*64+lane], hf2, E10);
        E10 = MFMA(wp[11*64+lane], hf3, E10);
        E11 = MFMA(wp[12*64+lane], hf0, E11);
        E11 = MFMA(wp[13*64+lane], hf1, E11);
        E11 = MFMA(wp[14*64+lane], hf2, E11);
        E11 = MFMA(wp[15*64+lane], hf3, E11);
        const h8 ef4 = pk8<0>(E10), ef5 = pk8<8>(E10), ef6 = pk8<0>(E11), ef7 = pk8<8>(E11);
        // enc1 + cross partials (f32 E10/E11 die here)
        float A1 = dot8h(ef5, onesh, dot8h(ef4, onesh, 0.f))
                 + dot8h(ef7, onesh, dot8h(ef6, onesh, 0.f));
        float D1 = dot8h(ef5, gw01, dot8h(ef4, gw00, 0.f))
                 + dot8h(ef7, gw11, dot8h(ef6, gw10, 0.f));
        float Q2 = dot8h(ef5, ef5, dot8h(ef4, ef4, 0.f))
                 + dot8h(ef7, ef7, dot8h(ef6, ef6, 0.f));
        float QX = dot8h(ef5, ef1, dot8h(ef4, ef0, 0.f))
                 + dot8h(ef7, ef3, dot8h(ef6, ef2, 0.f));
        // ---- gate1: K=128 = enc0 chunks 0..3 then enc1 chunks 4..7 ----
        f16x G0 = ld16(cstl + 128 + 16*hb);
        f16x G1 = ld16(cstl + 160 + 16*hb);
        G0 = MFMA(wp[1024+ 0*64+lane], ef0, G0);
        G0 = MFMA(wp[1024+ 1*64+lane], ef1, G0);
        G0 = MFMA(wp[1024+ 2*64+lane], ef2, G0);
        G0 = MFMA(wp[1024+ 3*64+lane], ef3, G0);
        G0 = MFMA(wp[1024+ 4*64+lane], ef4, G0);
        G0 = MFMA(wp[1024+ 5*64+lane], ef5, G0);
        G0 = MFMA(wp[1024+ 6*64+lane], ef6, G0);
        G0 = MFMA(wp[1024+ 7*64+lane], ef7, G0);
        G1 = MFMA(wp[1024+ 8*64+lane], ef0, G1);
        G1 = MFMA(wp[1024+ 9*64+lane], ef1, G1);
        G1 = MFMA(wp[1024+10*64+lane], ef2, G1);
        G1 = MFMA(wp[1024+11*64+lane], ef3, G1);
        G1 = MFMA(wp[1024+12*64+lane], ef4, G1);
        G1 = MFMA(wp[1024+13*64+lane], ef5, G1);
        G1 = MFMA(wp[1024+14*64+lane], ef6, G1);
        G1 = MFMA(wp[1024+15*64+lane], ef7, G1);
        G0 = xsig16(G0); G1 = xsig16(G1);
        // ---- gate2: pk G -> f16, fdot2 with wd (f16); f32 G dies here ----
        const h8 gf0 = pk8<0>(G0), gf1 = pk8<8>(G0), gf2 = pk8<0>(G1), gf3 = pk8<8>(G1);
        const h8 wd00 = wdf[2*hb], wd01 = wdf[2*hb+1];
        const h8 wd10 = wdf[4+2*hb], wd11 = wdf[4+2*hb+1];
        float part = dot8h(gf1, wd01, dot8h(gf0, wd00, 0.f))
                   + dot8h(gf3, wd11, dot8h(gf2, wd10, 0.f));
        part += __shfl_xor(part, 32);
        const float w1v = __builtin_amdgcn_rcpf(1.f + __builtin_amdgcn_exp2f(-(part + dlgb)*invT2));
        // ---- recombine partials: fu = (1-w)E0 + wE1 (never materialized) ----
        const float uv = 1.f - w1v;
        float sv = fmaf(w1v, A1 - A0, A0);
        float dt = fmaf(w1v, D1 - D0, D0);
        float sq = uv*uv*Q0 + 2.f*uv*w1v*QX + w1v*w1v*Q2;
        sv += __shfl_xor(sv, 32);
        sq += __shfl_xor(sq, 32);
        dt += __shfl_xor(dt, 32);
        const float mu = sv * (1.f/64.f);
        const float vv = sq * (1.f/64.f) - mu*mu;
        const float rs = __builtin_amdgcn_rsqf(vv + 1e-5f);
        const float o = fmaf(rs, dt - mu*C1, outc);
        if (lane < 32) out[p0 + lane] = o;
    }
}

extern "C" void kernel_launch(void* const* d_in, const int* in_sizes, int n_in,
                              void* d_out, int out_size, void* d_ws, size_t ws_size,
                              hipStream_t stream)
{
    const float* coords = (const float*)d_in[0];
    const float* cost   = (const float*)d_in[1];
    const float* lscale = (const float*)d_in[2];
    const float* W1     = (const float*)d_in[3];
    const float* b1     = (const float*)d_in[4];
    const float* W2     = (const float*)d_in[5];
    const float* b2     = (const float*)d_in[6];
    const float* fg     = (const float*)d_in[7];
    const float* fb     = (const float*)d_in[8];
    const float* Wg1    = (const float*)d_in[9];
    const float* bg1    = (const float*)d_in[10];
    const float* Wg2    = (const float*)d_in[11];
    const float* bg2    = (const float*)d_in[12];
    const float* gt     = (const float*)d_in[13];
    const float* lng    = (const float*)d_in[14];
    const float* lnb    = (const float*)d_in[15];
    const float* Wo     = (const float*)d_in[16];
    const float* bo     = (const float*)d_in[17];
    float* out = (float*)d_out;

    prep_kernel<<<20, 256, 0, stream>>>(W1, b1, W2, b2, fg, fb, Wg1, bg1, Wg2, lng, lnb, Wo);
    fused_kernel<<<BLOCKS, 256, 0, stream>>>(coords, cost, lscale, bg2, gt, bo, out);
}